// Round 4
// baseline (246.954 us; speedup 1.0000x reference)
//
#include <hip/hip_runtime.h>
#include <hip/hip_bf16.h>

// Problem constants (Qwen3-Next linear attention defaults)
#define S_LEN   256
#define HID     2048
#define NVH     32
#define DKD     128
#define DVD     128
#define KEYDIM  512
#define VALDIM  4096
#define CONVDIM 5120
#define QKVZ_N  9216
#define EPS_F   1e-6f

typedef __attribute__((ext_vector_type(8))) short bf16x8;
typedef __attribute__((ext_vector_type(4))) float f32x4;

__device__ __forceinline__ unsigned short f2bf(float f) {
    union { float f; unsigned int i; } v; v.f = f;
    unsigned int x = v.i;
    return (unsigned short)((x + 0x7FFFu + ((x >> 16) & 1u)) >> 16); // RNE
}
__device__ __forceinline__ unsigned int pk2(float x, float y) {
    union { __hip_bfloat162 h; unsigned int u; } c;
    c.h = __float22bfloat162_rn(float2{x, y});
    return c.u;
}
// 16B global -> LDS DMA. LDS dest = wave-uniform base + lane*16 (linear).
__device__ __forceinline__ void gl_lds16(const void* g, void* l) {
    __builtin_amdgcn_global_load_lds(
        (const __attribute__((address_space(1))) unsigned int*)g,
        (__attribute__((address_space(3))) unsigned int*)l,
        16, 0, 0);
}

// ---------------------------------------------------------------------------
// 2-phase split-K GEMM: Cpart[z] = A[256,Kc] @ B[N,Kc]^T.
// A bf16 [256][K] (DMA-staged), B fp32 [N][K] reg-staged -> bf16 in LDS.
// Tile: 128(M) x 64(N), BK=64. 256 thr = 4 waves (2Mx2N); wave = 64x32.
// LDS: As[2][128][64] + Bs[2][64][64] bf16 = 48KB -> 3 blocks/CU.
// Single barrier per K-step. B pipeline is 2-deep: loads for step it+2 are
// issued during step it; the cvt+ds_write for step it+1 goes into the buffer
// freed by the barrier ending step it-1, and lands behind the barrier ending
// step it (same barrier that drains the A DMA). M-tile pairs are dispatch-
// adjacent (blockIdx.x = n_tile*2 + m_tile) so both read B from the same
// XCD's L2. XOR-(row&7) chunk swizzle on both arrays; frag reads are the
// proven conflict-free b128 pattern (rounds 1-3: zero conflicts).
// ---------------------------------------------------------------------------
template<int NT>
__global__ __launch_bounds__(256, 3)
void gemm_db(const unsigned short* __restrict__ A, const float* __restrict__ B,
             float* __restrict__ Cpart, int N, int K, int kc) {
    __shared__ __align__(16) unsigned short As[2][128][64];
    __shared__ __align__(16) unsigned short Bs[2][NT][64];

    const int tid  = threadIdx.x;
    const int lane = tid & 63, wave = tid >> 6;
    const int wm = wave >> 1, wn = wave & 1;
    const int quad = lane >> 4, l16 = lane & 15;
    const int m0 = (blockIdx.x & 1) * 128;       // M-tile fastest: pair shares B
    const int n0 = (blockIdx.x >> 1) * NT;
    const int kbeg = blockIdx.y * kc;
    const int niter = kc >> 6;                   // BK = 64

    // A staging (DMA): 4 insts/wave; inst t covers rows wave*32+t*8 (+lane>>3).
    const int a_ro = lane >> 3;
    const int a_gc = (lane & 7) ^ a_ro;          // row&7 == lane>>3 (base%8==0)

    // B reg staging: thread owns row tid>>2, 16 consecutive floats at (tid&3)*16.
    const int rB = tid >> 2;
    const int cB = (tid & 3) * 16;
    const int swB = rB & 7;

    f32x4 acc[4][2];
#pragma unroll
    for (int i = 0; i < 4; i++)
#pragma unroll
        for (int j = 0; j < 2; j++) acc[i][j] = (f32x4){0.f, 0.f, 0.f, 0.f};

    float4 br[4];
    auto ldB = [&](int kk) {
        const float* p = B + (size_t)(n0 + rB) * K + kk + cB;
        br[0] = *(const float4*)(p);
        br[1] = *(const float4*)(p + 4);
        br[2] = *(const float4*)(p + 8);
        br[3] = *(const float4*)(p + 12);
    };
    auto wrB = [&](int buf) {
        uint4 u0, u1;
        u0.x = pk2(br[0].x, br[0].y); u0.y = pk2(br[0].z, br[0].w);
        u0.z = pk2(br[1].x, br[1].y); u0.w = pk2(br[1].z, br[1].w);
        u1.x = pk2(br[2].x, br[2].y); u1.y = pk2(br[2].z, br[2].w);
        u1.z = pk2(br[3].x, br[3].y); u1.w = pk2(br[3].z, br[3].w);
        int c0 = ((tid & 3) * 2) ^ swB;
        int c1 = ((tid & 3) * 2 + 1) ^ swB;
        *(uint4*)(&Bs[buf][rB][c0 * 8]) = u0;
        *(uint4*)(&Bs[buf][rB][c1 * 8]) = u1;
    };
    auto stageA = [&](int buf, int kk) {
#pragma unroll
        for (int t = 0; t < 4; ++t) {
            int rbase = wave * 32 + t * 8;
            gl_lds16(A + (size_t)(m0 + rbase + a_ro) * K + kk + a_gc * 8,
                     &As[buf][rbase][0]);
        }
    };
    auto compute = [&](int buf) {
#pragma unroll
        for (int ks = 0; ks < 2; ++ks) {
            bf16x8 af[4], bfr[2];
            int c = ((ks * 4 + quad) ^ (l16 & 7)) * 8;
#pragma unroll
            for (int i = 0; i < 4; ++i)
                af[i] = *(const bf16x8*)(&As[buf][wm * 64 + i * 16 + l16][c]);
#pragma unroll
            for (int j = 0; j < 2; ++j)
                bfr[j] = *(const bf16x8*)(&Bs[buf][wn * 32 + j * 16 + l16][c]);
#pragma unroll
            for (int i = 0; i < 4; ++i)
#pragma unroll
                for (int j = 0; j < 2; ++j)
                    acc[i][j] = __builtin_amdgcn_mfma_f32_16x16x32_bf16(af[i], bfr[j], acc[i][j], 0, 0, 0);
        }
    };

    // prologue: fill buf0 (A via DMA, B via regs), issue B loads for step 1
    ldB(kbeg);
    stageA(0, kbeg);
    wrB(0);
    if (niter > 1) ldB(kbeg + 64);
    __syncthreads();                             // buf0 ready

    for (int it = 0; it < niter; ++it) {
        if (it + 1 < niter) stageA((it + 1) & 1, kbeg + (it + 1) * 64);
        compute(it & 1);
        if (it + 1 < niter) wrB((it + 1) & 1);   // regs loaded one step ago
        if (it + 2 < niter) ldB(kbeg + (it + 2) * 64);
        __syncthreads();                         // next buf (DMA + ds_writes) ready
    }

    float* C = Cpart + (size_t)blockIdx.y * 256 * N;
#pragma unroll
    for (int i = 0; i < 4; i++)
#pragma unroll
        for (int j = 0; j < 2; j++)
#pragma unroll
            for (int r = 0; r < 4; r++) {
                int row = m0 + wm * 64 + i * 16 + quad * 4 + r;
                int col = n0 + wn * 32 + j * 16 + l16;
                C[(size_t)row * N + col] = acc[i][j][r];
            }
}

// sum P split-K partials (each n floats apart), float4-vectorized
template<int P>
__global__ void reduce_sum(const float* __restrict__ part, float* __restrict__ out, int n) {
    int i = (blockIdx.x * 256 + threadIdx.x) * 4;
    if (i >= n) return;
    float4 s = *(const float4*)(part + i);
#pragma unroll
    for (int p = 1; p < P; p++) {
        float4 v = *(const float4*)(part + (size_t)p * n + i);
        s.x += v.x; s.y += v.y; s.z += v.z; s.w += v.w;
    }
    *(float4*)(out + i) = s;
}

// ba = hidden @ w_ba^T : [256,64] + emit hs row in bf16 (A of GEMM1).
__global__ __launch_bounds__(256)
void ba_proj_cvt(const float* __restrict__ hs, const float* __restrict__ w_ba,
                 float* __restrict__ ba, unsigned short* __restrict__ abf) {
    int s = blockIdx.x;
    int n = threadIdx.x & 63, seg = threadIdx.x >> 6;
    const float* x = hs + (size_t)s * HID + seg * 512;
    const float* w = w_ba + (size_t)n * HID + seg * 512;
    float acc = 0.f;
#pragma unroll 4
    for (int k = 0; k < 512; k += 4) {
        float4 xv = *(const float4*)(x + k);
        float4 wv = *(const float4*)(w + k);
        acc += xv.x * wv.x + xv.y * wv.y + xv.z * wv.z + xv.w * wv.w;
    }
    __shared__ float parts[4][64];
    parts[seg][n] = acc;
    {   // bf16 copy of this row: thread converts 8 elems (L1-hot reread)
        int d = threadIdx.x * 8;
        const float4* p = (const float4*)(hs + (size_t)s * HID + d);
        float4 a = p[0], b = p[1];
        uint4 r;
        r.x = pk2(a.x, a.y); r.y = pk2(a.z, a.w);
        r.z = pk2(b.x, b.y); r.w = pk2(b.z, b.w);
        *(uint4*)(abf + (size_t)s * HID + d) = r;
    }
    __syncthreads();
    if (threadIdx.x < 64)
        ba[s * 64 + threadIdx.x] = parts[0][threadIdx.x] + parts[1][threadIdx.x]
                                 + parts[2][threadIdx.x] + parts[3][threadIdx.x];
}

// Fused: split-K sum of qkvz partials + causal depthwise conv(K=4) + silu for
// qkv cols (<5120), plain sum for z cols (>=5120, compact zs buffer).
// Thread = 4 cols (float4); block = 1024 cols x 8 s; conv window in regs.
template<int P>
__global__ __launch_bounds__(256)
void sum_conv(const float* __restrict__ part, const float* __restrict__ conv_w,
              float* __restrict__ conv, float* __restrict__ zs) {
    const int s0 = blockIdx.y * 8;
    const int c  = blockIdx.x * 1024 + threadIdx.x * 4;
    auto sum4 = [&](int s) {
        const float* p = part + (size_t)s * QKVZ_N + c;
        float4 v = *(const float4*)p;
#pragma unroll
        for (int q = 1; q < P; q++) {
            float4 w = *(const float4*)(p + (size_t)q * S_LEN * QKVZ_N);
            v.x += w.x; v.y += w.y; v.z += w.z; v.w += w.w;
        }
        return v;
    };
    if (c < CONVDIM) {
        float4 cw[4];
#pragma unroll
        for (int i = 0; i < 4; ++i) cw[i] = *(const float4*)(conv_w + (size_t)(c + i) * 4);
        float4 w0{0,0,0,0}, w1{0,0,0,0}, w2{0,0,0,0};
        for (int s = (s0 >= 3 ? s0 - 3 : 0); s < s0; ++s) { w0 = w1; w1 = w2; w2 = sum4(s); }
        for (int s = s0; s < s0 + 8; ++s) {
            float4 w3 = sum4(s);
            float4 o;
            o.x = w0.x * cw[0].x + w1.x * cw[0].y + w2.x * cw[0].z + w3.x * cw[0].w;
            o.y = w0.y * cw[1].x + w1.y * cw[1].y + w2.y * cw[1].z + w3.y * cw[1].w;
            o.z = w0.z * cw[2].x + w1.z * cw[2].y + w2.z * cw[2].z + w3.z * cw[2].w;
            o.w = w0.w * cw[3].x + w1.w * cw[3].y + w2.w * cw[3].z + w3.w * cw[3].w;
            o.x = o.x / (1.f + __expf(-o.x));
            o.y = o.y / (1.f + __expf(-o.y));
            o.z = o.z / (1.f + __expf(-o.z));
            o.w = o.w / (1.f + __expf(-o.w));
            *(float4*)(conv + (size_t)s * CONVDIM + c) = o;
            w0 = w1; w1 = w2; w2 = w3;
        }
    } else {
        for (int s = s0; s < s0 + 8; ++s) {
            float4 v = sum4(s);
            *(float4*)(zs + (size_t)s * VALDIM + (c - CONVDIM)) = v;
        }
    }
}

// scores[n][s][t] = (t<=s) ? (q[s]·k[t]) * DK^-0.5 * sigmoid(beta[t,n]+dt_bias[n]) : 0
// GQA: dot depends only on hk = n>>3 -> compute once, fan out over 8 v-heads.
// Triangular launch: blockIdx.x in [0,136) decodes to (s_tile >= t_tile).
__global__ __launch_bounds__(256)
void scores_k(const float* __restrict__ conv, const float* __restrict__ ba,
              const float* __restrict__ dt_bias, float* __restrict__ scores) {
    int p = blockIdx.x;
    int st = (int)((__fsqrt_rn(8.f * p + 1.f) - 1.f) * 0.5f);
    while ((st + 1) * (st + 2) / 2 <= p) st++;
    while (st * (st + 1) / 2 > p) st--;
    int tt = p - st * (st + 1) / 2;
    int hk = blockIdx.y;
    int s0 = st * 16, t0 = tt * 16;
    __shared__ float Qs[16][132], Ks[16][132];
    int tid = threadIdx.x;
    int qoff = hk * DKD;
    int koff = KEYDIM + hk * DKD;
    for (int idx = tid; idx < 16 * 128; idx += 256) {
        int i = idx >> 7, d = idx & 127;
        Qs[i][d] = conv[(size_t)(s0 + i) * CONVDIM + qoff + d];
        Ks[i][d] = conv[(size_t)(t0 + i) * CONVDIM + koff + d];
    }
    __syncthreads();
    int tx = tid & 15, ty = tid >> 4;
    int s = s0 + ty, t = t0 + tx;
    float dot = 0.f;
    for (int d = 0; d < 128; d++) dot += Qs[ty][d] * Ks[tx][d];
    float base = (t <= s) ? dot * 0.08838834764831845f : 0.f;
#pragma unroll
    for (int v = 0; v < 8; v++) {
        int n = hk * 8 + v;
        float b = ba[t * 64 + n] + dt_bias[n];
        float bg = 1.f / (1.f + __expf(-b));
        scores[((size_t)n * 256 + s) * 256 + t] = base * bg;
    }
}

// Fused attn + gated RMSNorm: attn[s][n][:] = sum_t scores[n][s][t]*v[t][n][:]
// stays in registers; 16-lane shfl_xor gives the row sum-of-squares; gate with
// silu(z); emit bf16 directly.
__global__ __launch_bounds__(256)
void attn_rms(const float* __restrict__ scores, const float* __restrict__ conv,
              const float* __restrict__ zs, const float* __restrict__ norm_w,
              unsigned short* __restrict__ normed) {
    int n = blockIdx.y, s0 = blockIdx.x * 16;
    int voff = 2 * KEYDIM + n * DVD;
    __shared__ float Ss[16][17];
    __shared__ float Vs[16][132];
    int tid = threadIdx.x, sy = tid >> 4, dx = tid & 15;
    float acc[8] = {0.f, 0.f, 0.f, 0.f, 0.f, 0.f, 0.f, 0.f};
    for (int t0 = 0; t0 <= s0; t0 += 16) {
        Ss[sy][dx] = scores[((size_t)n * 256 + s0 + sy) * 256 + t0 + dx];
        const float* vp = conv + (size_t)(t0 + sy) * CONVDIM + voff + dx * 8;
        *(float4*)&Vs[sy][dx * 8]     = *(const float4*)vp;
        *(float4*)&Vs[sy][dx * 8 + 4] = *(const float4*)(vp + 4);
        __syncthreads();
#pragma unroll
        for (int j = 0; j < 16; j++) {
            float sv = Ss[sy][j];
#pragma unroll
            for (int r = 0; r < 8; r++) acc[r] += sv * Vs[j][dx + 16 * r];
        }
        __syncthreads();
    }
    float ssq = 0.f;
#pragma unroll
    for (int r = 0; r < 8; r++) ssq += acc[r] * acc[r];
#pragma unroll
    for (int m = 1; m <= 8; m <<= 1) ssq += __shfl_xor(ssq, m, 64); // 16-lane group
    float inv = rsqrtf(ssq * (1.f / 128.f) + EPS_F);
    int s = s0 + sy;
#pragma unroll
    for (int r = 0; r < 8; r++) {
        int d = dx + 16 * r;
        float z = zs[(size_t)s * VALDIM + n * DVD + d];
        float sz = z / (1.f + __expf(-z));
        float v = acc[r] * inv * norm_w[d] * sz;
        normed[((size_t)s * NVH + n) * DVD + d] = f2bf(v);
    }
}

extern "C" void kernel_launch(void* const* d_in, const int* in_sizes, int n_in,
                              void* d_out, int out_size, void* d_ws, size_t ws_size,
                              hipStream_t stream) {
    const float* hs      = (const float*)d_in[0];
    const float* w_qkvz  = (const float*)d_in[1];
    const float* w_ba    = (const float*)d_in[2];
    const float* w_out   = (const float*)d_in[3];
    const float* conv_w  = (const float*)d_in[4];
    const float* dt_bias = (const float*)d_in[5];
    const float* norm_w  = (const float*)d_in[7];

    // Workspace overlay. Front: long-lived (abf, ba, conv, zs ~10.5 MB).
    // Region B: scratch1 (gemm1 partials) shares space with
    // normed/scratch2/scores (later stages).
    char* ws = (char*)d_ws;
    unsigned short* abf = (unsigned short*)ws; ws += (size_t)S_LEN * HID * 2;     // 1.05 MB
    float* ba   = (float*)ws;  ws += (size_t)S_LEN * 64 * 4;                      // 64 KB
    float* conv = (float*)ws;  ws += (size_t)S_LEN * CONVDIM * 4;                 // 5.24 MB
    float* zs   = (float*)ws;  ws += (size_t)S_LEN * VALDIM * 4;                  // 4.19 MB
    char* regB = ws;
    const bool big = ws_size >= (size_t)50 * 1024 * 1024;
    const int sk1 = big ? 4 : 2;   // gemm1 split-K
    const int sk2 = big ? 8 : 4;   // gemm2 split-K
    float* scratch1 = (float*)regB;                                   // sk1 x 9.44 MB
    unsigned short* normed = (unsigned short*)regB;                   // 2.10 MB
    float* scratch2 = (float*)(regB + 2097152);                       // sk2 x 2.10 MB
    float* scores   = (float*)(regB + 2097152 + (size_t)sk2 * 2097152); // 8.39 MB

    // 1) ba = X @ Wba^T  and hs -> bf16 A-operand
    ba_proj_cvt<<<S_LEN, 256, 0, stream>>>(hs, w_ba, ba, abf);
    // 2) qkvz partials = X @ Wqkvz^T  (M=256,N=9216,K=2048); M-pair adjacent
    gemm_db<64><<<dim3(2 * (QKVZ_N / 64), sk1), 256, 0, stream>>>(abf, w_qkvz, scratch1, QKVZ_N, HID, HID / sk1);
    // 3) fused split-K sum + causal conv + silu (qkv) / plain sum (z)
    if (big) sum_conv<4><<<dim3(9, 32), 256, 0, stream>>>(scratch1, conv_w, conv, zs);
    else     sum_conv<2><<<dim3(9, 32), 256, 0, stream>>>(scratch1, conv_w, conv, zs);
    // 4) causal scores, triangular grid (dot once per k-head, fan out 8 v-heads)
    scores_k<<<dim3(136, 4), 256, 0, stream>>>(conv, ba, dt_bias, scores);
    // 5) fused attn + gated RMSNorm -> bf16
    attn_rms<<<dim3(16, NVH), 256, 0, stream>>>(scores, conv, zs, norm_w, normed);
    // 6) out partials = normed @ Wout^T (M=256,N=2048,K=4096)
    gemm_db<64><<<dim3(2 * (HID / 64), sk2), 256, 0, stream>>>(normed, w_out, scratch2, HID, VALDIM, VALDIM / sk2);
    // 7) reduce split-K -> d_out (fp32)
    if (big) reduce_sum<8><<<(S_LEN * HID) / 1024, 256, 0, stream>>>(scratch2, (float*)d_out, S_LEN * HID);
    else     reduce_sum<4><<<(S_LEN * HID) / 1024, 256, 0, stream>>>(scratch2, (float*)d_out, S_LEN * HID);
}